// Round 15
// baseline (104.366 us; speedup 1.0000x reference)
//
#include <hip/hip_runtime.h>

// Binarized conv block via i8 MFMA implicit GEMM.
//   a = sign(x+bias1) in {+1,-1} (i8), zero-padded image [32][58][58][256] i8
//   qk = sign(kernel) in {+1,-1} (i8), pre-transposed to W_t[co][k]
//   conv == GEMM: C[pixel][co] = sum_k A_im2col[pixel][k] * W[k][co]
//   out = relu(C*scale[co] + shift[co])   (folded BN + bias2)
// i8 zero-pad == true conv zero-pad -> exact integers, no edge corrections.
//
// R14 post-mortem: step period 1786cyc, per-CU LDS reads 1542cyc (85B/cyc,
// m134) -> LDS-read-BW-bound (86%). Fragment traffic ~ (1/BMw+1/BNw); 64x64
// wave tiles need 1.85GB (35us floor > 30us MFMA floor). R15: 128x64 wave
// tiles (acc[8][4]) -> 1.39GB (26.5us floor < MFMA floor). Block = 128px x
// 256co (4 waves, BN=256, 784 blocks = 8x98 XCD-bijective). Schedule is
// R13/R14's proven one (stage-early, ONE vmcnt(0)+barrier per step, setprio
// cluster); only the wave decomposition changes this round.

typedef int v4i __attribute__((ext_vector_type(4)));
typedef unsigned int u32;

#define NB   32
#define HW   56
#define HP   58
#define HP2  (HP*HP)             // 3364
#define CIN  256
#define COUT 256
#define NPIX (NB*HW*HW)          // 100352
#define KTOT 2304
#define BM   128                 // pixels per block
#define BN   256                 // couts per block (all)
#define NSTEP 36                 // K steps of 64
#define NWG  (NPIX/BM)           // 784 = 8*98

#define PA_BYTES ((size_t)NB*HP*HP*CIN)     // 27,557,888
#define WT_OFF   PA_BYTES
#define WT_BYTES ((size_t)KTOT*COUT)        // 589,824
#define SC_OFF   (WT_OFF + WT_BYTES)
#define SH_OFF   (SC_OFF + 1024)

__device__ __forceinline__ void g2l16(const void* g, void* l) {
    __builtin_amdgcn_global_load_lds(
        (const __attribute__((address_space(1))) void*)g,
        (__attribute__((address_space(3))) void*)l, 16, 0, 0);
}

// ------- pack activations incl. pad ring: sign(x+bias1) or 0 -> i8 -------
__global__ __launch_bounds__(256) void pack_a_kernel(
    const float* __restrict__ x, const float* __restrict__ b1,
    signed char* __restrict__ pa)
{
    const int lane = threadIdx.x & 63;
    const int pp = blockIdx.x * 4 + (threadIdx.x >> 6);   // padded pixel
    const int n = pp / HP2, r = pp % HP2, ph = r / HP, pw = r % HP;
    const int ci = lane * 4;
    u32 o = 0;
    if (ph >= 1 && ph <= HW && pw >= 1 && pw <= HW) {     // wave-uniform branch
        const int pix = (n * HW + ph - 1) * HW + (pw - 1);
        const float4 xv = *(const float4*)(x + (size_t)pix * CIN + ci);
        const float4 bv = *(const float4*)(b1 + ci);
        o  = (u32)(unsigned char)((xv.x + bv.x >= 0.f) ? 1 : -1);
        o |= (u32)(unsigned char)((xv.y + bv.y >= 0.f) ? 1 : -1) << 8;
        o |= (u32)(unsigned char)((xv.z + bv.z >= 0.f) ? 1 : -1) << 16;
        o |= (u32)(unsigned char)((xv.w + bv.w >= 0.f) ? 1 : -1) << 24;
    }
    *(u32*)(pa + (size_t)pp * CIN + ci) = o;
    // grid = NB*HP*HP/4 = 26912
}

// ---------------- pack + transpose weights: W_t[co][k] i8 ----------------
__global__ __launch_bounds__(256) void packw_kernel(
    const float* __restrict__ k, signed char* __restrict__ wt)
{
    __shared__ signed char tile[64][256];
    const int t = threadIdx.x, k0 = blockIdx.x * 64;
    for (int j = 0; j < 64; ++j)
        tile[j][t] = (k[(size_t)(k0 + j) * COUT + t] >= 0.f) ? 1 : -1;
    __syncthreads();
    u32 wd[16];
#pragma unroll
    for (int j = 0; j < 16; ++j) wd[j] = 0;
#pragma unroll
    for (int j = 0; j < 64; ++j)
        wd[j >> 2] |= ((u32)(unsigned char)tile[j][t]) << ((j & 3) * 8);
    uint4* dst = (uint4*)(wt + (size_t)t * KTOT + k0);
#pragma unroll
    for (int j = 0; j < 4; ++j)
        dst[j] = make_uint4(wd[4*j], wd[4*j+1], wd[4*j+2], wd[4*j+3]);
    // grid = KTOT/64 = 36
}

// ---------------- fold BN + bias2 ----------------
__global__ __launch_bounds__(256) void bnprep_kernel(
    const float* __restrict__ beta, const float* __restrict__ mean,
    const float* __restrict__ var, const float* __restrict__ b2,
    float* __restrict__ scale, float* __restrict__ shift)
{
    const int t = threadIdx.x;
    const float s = rsqrtf(var[t] + 1e-3f);
    scale[t] = s;
    shift[t] = beta[t] - mean[t] * s + b2[t];
}

// ---------------- i8 implicit-GEMM conv + BN + relu ----------------
// 256 thr (4 waves); block = 128px x 256co; wave v owns 128px x couts
// [v*64, v*64+64): acc[8][4], 32 mfma_i32_16x16x64_i8 per K-step of 64.
__global__ __launch_bounds__(256, 2) void conv_mfma_kernel(
    const signed char* __restrict__ pa, const signed char* __restrict__ wt,
    const float* __restrict__ scale, const float* __restrict__ shift,
    float* __restrict__ out)
{
    // per buffer: A[128px][64B] = 8KB at 0, B[256co][64B] = 16KB at 8192
    __shared__ signed char L[2][24576];

    const int t = threadIdx.x, l = t & 63, v = t >> 6;
    // XCD swizzle (784 = 8 x 98, bijective)
    const int swz = (blockIdx.x & 7) * (NWG / 8) + (blockIdx.x >> 3);
    const int p0 = swz * BM;

    // A staging: thread t stages 16B slot (t&3) of pixels q, q+64 (q = t>>2)
    const signed char* abase[2];
#pragma unroll
    for (int i = 0; i < 2; ++i) {
        const int q = (t >> 2) + i * 64;
        const int p = p0 + q;
        const int n = p / 3136, r = p % 3136, h = r / 56, w = r % 56;
        const int aswz = (((t & 3) ^ ((q >> 1) & 3)) << 4);  // source pre-swizzle
        abase[i] = pa + ((size_t)(n * HP + h) * HP + w) * CIN + aswz;
    }
    // B staging: thread t stages slot (t&3) of W-rows r = (t>>2) + j*64
    const signed char* wbase[4];
#pragma unroll
    for (int j = 0; j < 4; ++j) {
        const int r = j * 64 + (t >> 2);
        const int bswz = (((t & 3) ^ ((r >> 1) & 3)) << 4);
        wbase[j] = wt + (size_t)r * KTOT + bswz;
    }

    // fragment ds_read byte offsets (swizzled reads match pre-swizzled src)
    int aoff[8], boff[4];
#pragma unroll
    for (int pg = 0; pg < 8; ++pg) {
        const int row = pg * 16 + (l & 15);
        aoff[pg] = row * 64 + ((((l >> 4) ^ (row >> 1)) & 3) << 4);
    }
#pragma unroll
    for (int cg = 0; cg < 4; ++cg) {
        const int row = v * 64 + cg * 16 + (l & 15);
        boff[cg] = 8192 + row * 64 + ((((l >> 4) ^ (row >> 1)) & 3) << 4);
    }

    v4i acc[8][4];
#pragma unroll
    for (int i = 0; i < 8; ++i)
#pragma unroll
        for (int j = 0; j < 4; ++j) acc[i][j] = (v4i){0, 0, 0, 0};

    auto goffA = [&](int s) {
        const int tap = s >> 2, cq = s & 3;
        const int ty = tap / 3, tx = tap - ty * 3;
        return ((ty * HP + tx) << 8) + (cq << 6);
    };
    auto STAGE = [&](int buf, int s) {         // 6 g2l16 per thread
        const int go = goffA(s);
        g2l16(abase[0] + go, &L[buf][v * 1024]);
        g2l16(abase[1] + go, &L[buf][4096 + v * 1024]);
#pragma unroll
        for (int j = 0; j < 4; ++j)
            g2l16(wbase[j] + (s << 6), &L[buf][8192 + j * 4096 + v * 1024]);
    };

    // prologue
    STAGE(0, 0);
    asm volatile("s_waitcnt vmcnt(0)" ::: "memory");
    __builtin_amdgcn_s_barrier();

#pragma unroll 1
    for (int s = 0; s < NSTEP; ++s) {
        const int cur = s & 1, nxt = cur ^ 1;
        const signed char* Lc = &L[cur][0];
        if (s + 1 < NSTEP) STAGE(nxt, s + 1);  // issue early; lands by step end
        // read all fragments of cur (compiler inserts lgkmcnt before MFMA)
        v4i bf0 = *(const v4i*)(Lc + boff[0]);
        v4i bf1 = *(const v4i*)(Lc + boff[1]);
        v4i bf2 = *(const v4i*)(Lc + boff[2]);
        v4i bf3 = *(const v4i*)(Lc + boff[3]);
        v4i af[8];
#pragma unroll
        for (int pg = 0; pg < 8; ++pg) af[pg] = *(const v4i*)(Lc + aoff[pg]);
        __builtin_amdgcn_s_setprio(1);
#pragma unroll
        for (int pg = 0; pg < 8; ++pg) {
            acc[pg][0] = __builtin_amdgcn_mfma_i32_16x16x64_i8(af[pg], bf0, acc[pg][0], 0, 0, 0);
            acc[pg][1] = __builtin_amdgcn_mfma_i32_16x16x64_i8(af[pg], bf1, acc[pg][1], 0, 0, 0);
            acc[pg][2] = __builtin_amdgcn_mfma_i32_16x16x64_i8(af[pg], bf2, acc[pg][2], 0, 0, 0);
            acc[pg][3] = __builtin_amdgcn_mfma_i32_16x16x64_i8(af[pg], bf3, acc[pg][3], 0, 0, 0);
        }
        __builtin_amdgcn_s_setprio(0);
        // stage(s+1) landed + all waves done reading cur (reads precede MFMAs)
        asm volatile("s_waitcnt vmcnt(0)" ::: "memory");
        __builtin_amdgcn_s_barrier();
    }

    // epilogue: C col = l&15 (co), row = (l>>4)*4 + reg (pixel)   [m89 layout]
#pragma unroll
    for (int cg = 0; cg < 4; ++cg) {
        const int co = v * 64 + cg * 16 + (l & 15);
        const float sc = scale[co], sh = shift[co];
#pragma unroll
        for (int pg = 0; pg < 8; ++pg) {
            const int prow0 = p0 + pg * 16 + (l >> 4) * 4;
#pragma unroll
            for (int rr = 0; rr < 4; ++rr) {
                const float y = (float)acc[pg][cg][rr];
                out[(size_t)(prow0 + rr) * COUT + co] = fmaxf(fmaf(y, sc, sh), 0.f);
            }
        }
    }
}

extern "C" void kernel_launch(void* const* d_in, const int* in_sizes, int n_in,
                              void* d_out, int out_size, void* d_ws, size_t ws_size,
                              hipStream_t stream)
{
    const float* x      = (const float*)d_in[0];
    const float* bias1  = (const float*)d_in[1];
    const float* kernel = (const float*)d_in[2];
    const float* bn_beta = (const float*)d_in[3];
    const float* bn_mean = (const float*)d_in[4];
    const float* bn_var  = (const float*)d_in[5];
    const float* bias2   = (const float*)d_in[6];
    float* out = (float*)d_out;

    signed char* pa  = (signed char*)d_ws;                // padded i8 image
    signed char* wtp = (signed char*)d_ws + WT_OFF;       // W_t[co][k]
    float* scale = (float*)((char*)d_ws + SC_OFF);
    float* shift = (float*)((char*)d_ws + SH_OFF);

    pack_a_kernel<<<dim3(NB * HP2 / 4), dim3(256), 0, stream>>>(x, bias1, pa);
    packw_kernel<<<dim3(KTOT / 64), dim3(256), 0, stream>>>(kernel, wtp);
    bnprep_kernel<<<dim3(1), dim3(256), 0, stream>>>(bn_beta, bn_mean, bn_var, bias2,
                                                     scale, shift);
    conv_mfma_kernel<<<dim3(NWG), dim3(256), 0, stream>>>(pa, wtp, scale, shift, out);
}